// Round 16
// baseline (473.873 us; speedup 1.0000x reference)
//
#include <hip/hip_runtime.h>
#include <hip/hip_bf16.h>
#include <stdint.h>

typedef short    s16x8  __attribute__((ext_vector_type(8)));
typedef __bf16   bf16x8 __attribute__((ext_vector_type(8)));
typedef float    f32x4  __attribute__((ext_vector_type(4)));

__device__ __forceinline__ unsigned short f2bf(float f) {
    union { float f; unsigned u; } v; v.f = f;
    unsigned r = v.u + 0x7FFFu + ((v.u >> 16) & 1u);
    return (unsigned short)(r >> 16);
}
__device__ __forceinline__ float bf2f(unsigned short s) {
    union { unsigned u; float f; } v; v.u = ((unsigned)s) << 16;
    return v.f;
}

__device__ __forceinline__ void gload16(const void* g, void* l) {
    __builtin_amdgcn_global_load_lds(
        (const __attribute__((address_space(1))) void*)(uintptr_t)g,
        (__attribute__((address_space(3))) void*)(uintptr_t)l,
        16, 0, 0);
}

// ---------------- fp32 -> bf16 conversion (x and weights) -------------------
__global__ __launch_bounds__(256) void cvt_bf16(const float* __restrict__ in,
                                                unsigned short* __restrict__ out,
                                                int n4) {
    int i = blockIdx.x * blockDim.x + threadIdx.x;
    int stride = gridDim.x * blockDim.x;
    for (; i < n4; i += stride) {
        const float4 v = *(const float4*)(in + (size_t)i * 4);
        ushort4 o;
        o.x = f2bf(v.x); o.y = f2bf(v.y); o.z = f2bf(v.z); o.w = f2bf(v.w);
        *(ushort4*)(out + (size_t)i * 4) = o;
    }
}

// ---------------- 128x128 bf16 GEMM, BK=64 (R11-exact — best GEMM: 130 us) --
template<int K, bool OUT_BF16>
__global__ __launch_bounds__(256, 2) void gemm128(
        const unsigned short* __restrict__ A,   // [M][K] bf16
        const unsigned short* __restrict__ B,   // [N][K] bf16
        const float* __restrict__ bias,         // [N] fp32
        void* __restrict__ Cvoid,               // [M][N] bf16 or fp32
        int M, int N, int ntn) {
    constexpr int BM = 128, BN = 128, BK = 64, NT = K / BK;   // NT = 8
    __shared__ __align__(16) unsigned short As[2][BM * BK];   // 2 x 16 KiB
    __shared__ __align__(16) unsigned short Bs[2][BN * BK];   // 2 x 16 KiB
    const int tid  = threadIdx.x;
    const int lane = tid & 63;
    const int wv   = tid >> 6;                  // 4 waves
    const int nwg  = (int)gridDim.x;
    const int wg   = ((int)blockIdx.x & 7) * (nwg >> 3) + ((int)blockIdx.x >> 3);
    const int bm   = wg / ntn;
    const int bn   = wg % ntn;
    const int wr   = (wv >> 1) * 64;
    const int wc   = (wv & 1) * 64;
    const int lr   = lane & 15;
    const int ls   = lane >> 4;

    const unsigned short* Ag = A + (size_t)bm * BM * K;
    const unsigned short* Bg = B + (size_t)bn * BN * K;

    auto stage = [&](int t) {
        char* la = (char*)As[t & 1];
        char* lb = (char*)Bs[t & 1];
        #pragma unroll
        for (int p = 0; p < 4; ++p) {
            const int c     = p * 256 + tid;
            const int row   = c >> 3;                  // 8 x 16B chunks per row
            const int slot  = c & 7;
            const int gslot = slot ^ (row & 7);        // T2 involution
            gload16(Ag + (size_t)row * K + t * BK + gslot * 8, la + c * 16);
            gload16(Bg + (size_t)row * K + t * BK + gslot * 8, lb + c * 16);
        }
    };
    auto frag = [&](const unsigned short* lds, int row, int ks) -> bf16x8 {
        const int slot = ks ^ (row & 7);
        return *(const bf16x8*)((const char*)lds + row * (BK * 2) + slot * 16);
    };

    f32x4 acc[4][4] = {};

    stage(0);

    #pragma unroll
    for (int t = 0; t < NT; ++t) {
        asm volatile("s_waitcnt vmcnt(0)" ::: "memory");
        __syncthreads();
        if (t + 1 < NT) stage(t + 1);

        bf16x8 af[2][4], bf[2][4];
        #pragma unroll
        for (int h = 0; h < 2; ++h) {
            #pragma unroll
            for (int m = 0; m < 4; ++m)
                af[h][m] = frag(As[t & 1], wr + m * 16 + lr, h * 4 + ls);
            #pragma unroll
            for (int n = 0; n < 4; ++n)
                bf[h][n] = frag(Bs[t & 1], wc + n * 16 + lr, h * 4 + ls);
        }

        __builtin_amdgcn_s_setprio(1);
        #pragma unroll
        for (int h = 0; h < 2; ++h)
            #pragma unroll
            for (int m = 0; m < 4; ++m)
                #pragma unroll
                for (int n = 0; n < 4; ++n)
                    acc[m][n] = __builtin_amdgcn_mfma_f32_16x16x32_bf16(
                        af[h][m], bf[h][n], acc[m][n], 0, 0, 0);
        __builtin_amdgcn_s_setprio(0);
    }

    const int r0 = bm * BM + wr + ls * 4;
    const int c0 = bn * BN + wc + lr;
    #pragma unroll
    for (int n = 0; n < 4; ++n) {
        const int gc = c0 + n * 16;
        const float bv = bias[gc];
        #pragma unroll
        for (int m = 0; m < 4; ++m) {
            #pragma unroll
            for (int j = 0; j < 4; ++j) {
                const int gr = r0 + m * 16 + j;
                const float v = acc[m][n][j] + bv;
                if constexpr (OUT_BF16)
                    ((unsigned short*)Cvoid)[(size_t)gr * N + gc] = f2bf(v);
                else
                    ((float*)Cvoid)[(size_t)gr * N + gc] = v;
            }
        }
    }
}

// ---------------- GEMM2 with FUSED per-token head-attention -----------------
// out[M][512] = val @ Wout^T + b, where val is computed IN the A-staging:
// K-slab t (BK=64) of val == head t's output: val[tok][t*64+d] =
//   sum_g P[tok][t][g] * qkv[tok][g*192+128+d].
// Prologue computes P[8 heads][128 tok][8 g] once per block (VALU dots +
// softmax; 2 threads/token, 4 heads each), stores bf16 in 16 KB LDS.
// Per window t: build val slab t+1 in registers (8 P-weighted V strips,
// L2/L3-served re-reads) and ds_write into the SAME swizzled As layout the
// R11 frag reader uses. B (Wout) staging, window loop, MFMA, epilogue are
// R11-exact. Deletes the attn kernel and the val HBM round-trip.
// LDS 80 KB -> 2 blocks/CU. T1 XCD swizzle, T5 setprio.
template<int K>   // K = 512
__global__ __launch_bounds__(256, 2) void gemm2_attn(
        const unsigned short* __restrict__ QKV,   // [M][1536] bf16
        const unsigned short* __restrict__ W,     // [512][512] bf16 (w_out)
        const float* __restrict__ bias,           // [512] fp32
        float* __restrict__ OUT,                  // [M][512] fp32
        int M, int N, int ntn) {
    constexpr int BM = 128, BN = 128, BK = 64, NT = K / BK;   // NT = 8 heads
    __shared__ __align__(16) unsigned short As[2][BM * BK];   // val slabs 32 KB
    __shared__ __align__(16) unsigned short Bs[2][BN * BK];   // W slabs  32 KB
    __shared__ __align__(16) unsigned short Pl[8][128][8];    // P bf16   16 KB
    const int tid  = threadIdx.x;
    const int lane = tid & 63;
    const int wv   = tid >> 6;
    const int nwg  = (int)gridDim.x;
    const int wg   = ((int)blockIdx.x & 7) * (nwg >> 3) + ((int)blockIdx.x >> 3);
    const int bm   = wg / ntn;
    const int bn   = wg % ntn;
    const int wr   = (wv >> 1) * 64;
    const int wc   = (wv & 1) * 64;
    const int lr   = lane & 15;
    const int ls   = lane >> 4;

    const unsigned short* qkvb = QKV + (size_t)bm * BM * 1536;
    const unsigned short* Bg   = W + (size_t)bn * BN * K;

    // ---- prologue: P[tok][h][g].  thread = (token tk, head-half) ----
    {
        const int tk = tid >> 1;
        const int h0 = (tid & 1) * 4;
        const unsigned short* row = qkvb + (size_t)tk * 1536;
        float s[4][8] = {};
        #pragma unroll
        for (int dc = 0; dc < 8; ++dc) {          // 8 d-chunks of 8
            float qf[4][8], kf[8][8];
            #pragma unroll
            for (int h = 0; h < 4; ++h) {
                s16x8 v = *(const s16x8*)(row + (h0 + h) * 192 + dc * 8);
                #pragma unroll
                for (int j = 0; j < 8; ++j) qf[h][j] = bf2f((unsigned short)v[j]);
            }
            #pragma unroll
            for (int g = 0; g < 8; ++g) {
                s16x8 v = *(const s16x8*)(row + g * 192 + 64 + dc * 8);
                #pragma unroll
                for (int j = 0; j < 8; ++j) kf[g][j] = bf2f((unsigned short)v[j]);
            }
            #pragma unroll
            for (int h = 0; h < 4; ++h)
                #pragma unroll
                for (int g = 0; g < 8; ++g)
                    #pragma unroll
                    for (int j = 0; j < 8; ++j)
                        s[h][g] += qf[h][j] * kf[g][j];
        }
        #pragma unroll
        for (int h = 0; h < 4; ++h) {
            float mx = -1e30f;
            #pragma unroll
            for (int g = 0; g < 8; ++g) { s[h][g] *= 0.125f; mx = fmaxf(mx, s[h][g]); }
            float sum = 0.f;
            #pragma unroll
            for (int g = 0; g < 8; ++g) { s[h][g] = __expf(s[h][g] - mx); sum += s[h][g]; }
            const float inv = 1.f / sum;
            s16x8 o;
            #pragma unroll
            for (int g = 0; g < 8; ++g) o[g] = (short)f2bf(s[h][g] * inv);
            *(s16x8*)(&Pl[h0 + h][tk][0]) = o;
        }
    }

    auto stageB = [&](int t) {
        char* lb = (char*)Bs[t & 1];
        #pragma unroll
        for (int p = 0; p < 4; ++p) {             // 16 KB = 1024 chunks
            const int c     = p * 256 + tid;
            const int row   = c >> 3;
            const int slot  = c & 7;
            const int gslot = slot ^ (row & 7);
            gload16(Bg + (size_t)row * K + t * BK + gslot * 8, lb + c * 16);
        }
    };
    auto frag = [&](const unsigned short* lds, int row, int ks) -> bf16x8 {
        const int slot = ks ^ (row & 7);
        return *(const bf16x8*)((const char*)lds + row * (BK * 2) + slot * 16);
    };

    // Build val slab for head/window t: thread = (token tk, 32-col half).
    const int tk   = tid >> 1;
    const int half = tid & 1;
    auto makeVal = [&](int t) {
        s16x8 pv = *(const s16x8*)(&Pl[t][tk][0]);
        float pf[8];
        #pragma unroll
        for (int g = 0; g < 8; ++g) pf[g] = bf2f((unsigned short)pv[g]);
        float o[32] = {};
        #pragma unroll
        for (int g = 0; g < 8; ++g) {
            const unsigned short* vb =
                qkvb + (size_t)tk * 1536 + g * 192 + 128 + half * 32;
            #pragma unroll
            for (int j = 0; j < 4; ++j) {
                s16x8 v = *(const s16x8*)(vb + j * 8);
                #pragma unroll
                for (int e = 0; e < 8; ++e)
                    o[j * 8 + e] += pf[g] * bf2f((unsigned short)v[e]);
            }
        }
        char* la = (char*)As[t & 1];
        #pragma unroll
        for (int j = 0; j < 4; ++j) {
            const int cc   = half * 4 + j;
            const int slot = cc ^ (tk & 7);        // match frag-read swizzle
            s16x8 w8;
            #pragma unroll
            for (int e = 0; e < 8; ++e) w8[e] = (short)f2bf(o[j * 8 + e]);
            *(s16x8*)(la + (tk * 8 + slot) * 16) = w8;
        }
    };

    f32x4 acc[4][4] = {};

    __syncthreads();          // P visible to all threads
    stageB(0);
    makeVal(0);

    #pragma unroll
    for (int t = 0; t < NT; ++t) {
        asm volatile("s_waitcnt vmcnt(0)" ::: "memory");
        __syncthreads();               // B(t) landed, val(t) writes visible
        if (t + 1 < NT) stageB(t + 1);

        bf16x8 af[2][4], bf[2][4];
        #pragma unroll
        for (int h = 0; h < 2; ++h) {
            #pragma unroll
            for (int m = 0; m < 4; ++m)
                af[h][m] = frag(As[t & 1], wr + m * 16 + lr, h * 4 + ls);
            #pragma unroll
            for (int n = 0; n < 4; ++n)
                bf[h][n] = frag(Bs[t & 1], wc + n * 16 + lr, h * 4 + ls);
        }

        __builtin_amdgcn_s_setprio(1);
        #pragma unroll
        for (int h = 0; h < 2; ++h)
            #pragma unroll
            for (int m = 0; m < 4; ++m)
                #pragma unroll
                for (int n = 0; n < 4; ++n)
                    acc[m][n] = __builtin_amdgcn_mfma_f32_16x16x32_bf16(
                        af[h][m], bf[h][n], acc[m][n], 0, 0, 0);
        __builtin_amdgcn_s_setprio(0);

        if (t + 1 < NT) makeVal(t + 1);   // V-load latency hides under the
                                          // other wave's MFMA (2 waves/SIMD)
    }

    const int r0 = bm * BM + wr + ls * 4;
    const int c0 = bn * BN + wc + lr;
    #pragma unroll
    for (int n = 0; n < 4; ++n) {
        const int gc = c0 + n * 16;
        const float bv = bias[gc];
        #pragma unroll
        for (int m = 0; m < 4; ++m) {
            #pragma unroll
            for (int j = 0; j < 4; ++j) {
                const int gr = r0 + m * 16 + j;
                OUT[(size_t)gr * N + gc] = acc[m][n][j] + bv;
            }
        }
    }
}

// ---------------------------------------------------------------------------
extern "C" void kernel_launch(void* const* d_in, const int* in_sizes, int n_in,
                              void* d_out, int out_size, void* d_ws, size_t ws_size,
                              hipStream_t stream) {
    const float* x     = (const float*)d_in[0];
    const float* w_qkv = (const float*)d_in[1];
    const float* b_qkv = (const float*)d_in[2];
    const float* w_out = (const float*)d_in[3];
    const float* b_out = (const float*)d_in[4];
    float* out = (float*)d_out;

    const int DM = 512;
    const int M  = in_sizes[0] / DM;      // 61440 tokens

    unsigned short* xb    = (unsigned short*)d_ws;          // M*512
    unsigned short* wqkvb = xb + (size_t)M * DM;            // 1536*512
    unsigned short* woutb = wqkvb + (size_t)3 * DM * DM;    // 512*512
    unsigned short* qkvb  = woutb + (size_t)DM * DM;        // M*1536

    cvt_bf16<<<2048, 256, 0, stream>>>(x, xb, M * DM / 4);
    cvt_bf16<<<96,   256, 0, stream>>>(w_qkv, wqkvb, 3 * DM * DM / 4);
    cvt_bf16<<<32,   256, 0, stream>>>(w_out, woutb, DM * DM / 4);

    // GEMM1: qkv[M][1536] = x @ w_qkv^T + b_qkv (bf16 out). grid 480*12=5760
    gemm128<512, true><<<dim3((M / 128) * (3 * DM / 128)), 256, 0, stream>>>(
        xb, wqkvb, b_qkv, qkvb, M, 3 * DM, 3 * DM / 128);

    // GEMM2 + fused attention: out = attn(qkv) @ w_out^T + b_out. grid 1920
    gemm2_attn<512><<<dim3((M / 128) * (DM / 128)), 256, 0, stream>>>(
        qkvb, woutb, b_out, out, M, DM, DM / 128);
}

// Round 17
// 308.665 us; speedup vs baseline: 1.5352x; 1.5352x over previous
//
#include <hip/hip_runtime.h>
#include <hip/hip_bf16.h>
#include <stdint.h>

typedef short    s16x8  __attribute__((ext_vector_type(8)));
typedef __bf16   bf16x8 __attribute__((ext_vector_type(8)));
typedef float    f32x4  __attribute__((ext_vector_type(4)));

__device__ __forceinline__ unsigned short f2bf(float f) {
    union { float f; unsigned u; } v; v.f = f;
    unsigned r = v.u + 0x7FFFu + ((v.u >> 16) & 1u);
    return (unsigned short)(r >> 16);
}
__device__ __forceinline__ float bf2f(unsigned short s) {
    union { unsigned u; float f; } v; v.u = ((unsigned)s) << 16;
    return v.f;
}

__device__ __forceinline__ void gload16(const void* g, void* l) {
    __builtin_amdgcn_global_load_lds(
        (const __attribute__((address_space(1))) void*)(uintptr_t)g,
        (__attribute__((address_space(3))) void*)(uintptr_t)l,
        16, 0, 0);
}

#define MFMA(a, b, c) __builtin_amdgcn_mfma_f32_16x16x32_bf16((a), (b), (c), 0, 0, 0)

// ---------------- fp32 -> bf16 conversion -----------------------------------
__global__ __launch_bounds__(256) void cvt_bf16(const float* __restrict__ in,
                                                unsigned short* __restrict__ out,
                                                int n4) {
    int i = blockIdx.x * blockDim.x + threadIdx.x;
    int stride = gridDim.x * blockDim.x;
    for (; i < n4; i += stride) {
        const float4 v = *(const float4*)(in + (size_t)i * 4);
        ushort4 o;
        o.x = f2bf(v.x); o.y = f2bf(v.y); o.z = f2bf(v.z); o.w = f2bf(v.w);
        *(ushort4*)(out + (size_t)i * 4) = o;
    }
}

// ---------------- 256x256 GEMM — faithful phase-split + counted vmcnt -------
// 8 waves (2M x 4N), 128x64 C per wave, BK=64, NT=8. Per K-tile: 4 phases
// {reads + 1 half-tile stage + barrier + lgkmcnt(0) + setprio + 16 MFMA +
// setprio + barrier}; loop-top vmcnt(4) keeps A(t+1)'s 4 loads IN FLIGHT
// across the barrier (T4 counted-vmcnt — the m218 lever, only active inside
// a phase-split schedule). Race-derivation in session notes: A(t+2) staged
// ph2/ph3 strictly after all A(t) reads (ph1-end barrier); B(t+1) opposite
// parity from B(t) reads; prologue = A(0),B(0),A(1) (12 loads) -> vmcnt(4);
// tail t=NT-1 -> vmcnt(0). sched_barrier(0) pins reads below the publishing
// barrier (rule 18/21 class). T1 XCD swizzle, T2 source-XOR swizzle, T5.
template<int K, bool OUT_BF16>
__global__ __launch_bounds__(512, 2) void gemm8p(
        const unsigned short* __restrict__ A,   // [M][K] bf16
        const unsigned short* __restrict__ B,   // [N][K] bf16
        const float* __restrict__ bias,         // [N] fp32
        void* __restrict__ Cvoid,               // [M][N] bf16 or fp32
        int M, int N, int ntn) {
    constexpr int BM = 256, BN = 256, BK = 64, NT = K / BK;   // NT = 8
    __shared__ __align__(16) unsigned short Ah[2][2][128 * BK];  // 64 KiB
    __shared__ __align__(16) unsigned short Bh[2][2][128 * BK];  // 64 KiB
    const int tid  = threadIdx.x;
    const int lane = tid & 63;
    const int wv   = tid >> 6;            // 8 waves: 2M x 4N
    const int nwg  = (int)gridDim.x;
    const int wg   = ((int)blockIdx.x & 7) * (nwg >> 3) + ((int)blockIdx.x >> 3);
    const int bm   = wg / ntn;
    const int bn   = wg % ntn;
    const int wr   = (wv >> 2) * 128;     // 0 / 128
    const int wc   = (wv & 3) * 64;       // 0 / 64 / 128 / 192
    const int ahf  = wv >> 2;             // this wave's A half
    const int bhf  = (wv & 3) >> 1;       // this wave's B half
    const int nb   = wc & 127;            // row base within B half (0/64)
    const int lr   = lane & 15;
    const int ls   = lane >> 4;           // k-slot 0..3 within a K=32 half

    const unsigned short* Ag = A + (size_t)bm * BM * K;
    const unsigned short* Bg = B + (size_t)bn * BN * K;

    // Stage one 128x64 half-tile (1024 x 16B chunks, 2/thread). Linear LDS
    // dest; T2 swizzle on the global source slot (involution, 8 slots/row).
    auto stageA = [&](int t, int h) {
        char* l = (char*)Ah[t & 1][h];
        #pragma unroll
        for (int p = 0; p < 2; ++p) {
            const int c = p * 512 + tid;
            const int row = c >> 3, slot = c & 7;
            const int gs = slot ^ (row & 7);
            gload16(Ag + (size_t)(h * 128 + row) * K + t * BK + gs * 8, l + c * 16);
        }
    };
    auto stageB = [&](int t, int h) {
        char* l = (char*)Bh[t & 1][h];
        #pragma unroll
        for (int p = 0; p < 2; ++p) {
            const int c = p * 512 + tid;
            const int row = c >> 3, slot = c & 7;
            const int gs = slot ^ (row & 7);
            gload16(Bg + (size_t)(h * 128 + row) * K + t * BK + gs * 8, l + c * 16);
        }
    };
    auto fragA = [&](int t, int row, int ks) -> bf16x8 {   // row local to half
        const int slot = ks ^ (row & 7);
        return *(const bf16x8*)((const char*)Ah[t & 1][ahf] + row * 128 + slot * 16);
    };
    auto fragB = [&](int t, int row, int ks) -> bf16x8 {
        const int slot = ks ^ (row & 7);
        return *(const bf16x8*)((const char*)Bh[t & 1][bhf] + row * 128 + slot * 16);
    };

    f32x4 acc[8][4] = {};

    stageA(0, 0); stageA(0, 1); stageB(0, 0); stageB(0, 1);
    stageA(1, 0); stageA(1, 1);          // 12 loads/thread in flight

    #pragma unroll
    for (int t = 0; t < NT; ++t) {
        if (t < NT - 1) asm volatile("s_waitcnt vmcnt(4)" ::: "memory");
        else            asm volatile("s_waitcnt vmcnt(0)" ::: "memory");
        __builtin_amdgcn_s_barrier();        // tile t published (all waves)
        __builtin_amdgcn_sched_barrier(0);   // pin reads below the barrier

        // ---- ph0: reads {afA,afB,bfA}; stage B0(t+1); MFMA m0-3 x k0 ----
        bf16x8 afA[4], afB[4], bfA[4];
        #pragma unroll
        for (int m = 0; m < 4; ++m) {
            afA[m] = fragA(t, m * 16 + lr, ls);
            afB[m] = fragA(t, m * 16 + lr, 4 + ls);
        }
        #pragma unroll
        for (int n = 0; n < 4; ++n) bfA[n] = fragB(t, nb + n * 16 + lr, ls);
        if (t + 1 < NT) stageB(t + 1, 0);
        __builtin_amdgcn_s_barrier();
        asm volatile("s_waitcnt lgkmcnt(0)" ::: "memory");
        __builtin_amdgcn_s_setprio(1);
        #pragma unroll
        for (int m = 0; m < 4; ++m)
            #pragma unroll
            for (int n = 0; n < 4; ++n)
                acc[m][n] = MFMA(afA[m], bfA[n], acc[m][n]);
        __builtin_amdgcn_s_setprio(0);
        __builtin_amdgcn_s_barrier();

        // ---- ph1: reads {a2A,a2B,bfB}; stage B1(t+1); MFMA m4-7 x k0 ----
        bf16x8 a2A[4], a2B[4], bfB[4];
        #pragma unroll
        for (int m = 0; m < 4; ++m) {
            a2A[m] = fragA(t, 64 + m * 16 + lr, ls);
            a2B[m] = fragA(t, 64 + m * 16 + lr, 4 + ls);
        }
        #pragma unroll
        for (int n = 0; n < 4; ++n) bfB[n] = fragB(t, nb + n * 16 + lr, 4 + ls);
        if (t + 1 < NT) stageB(t + 1, 1);
        __builtin_amdgcn_s_barrier();
        asm volatile("s_waitcnt lgkmcnt(0)" ::: "memory");
        __builtin_amdgcn_s_setprio(1);
        #pragma unroll
        for (int m = 0; m < 4; ++m)
            #pragma unroll
            for (int n = 0; n < 4; ++n)
                acc[4 + m][n] = MFMA(a2A[m], bfA[n], acc[4 + m][n]);
        __builtin_amdgcn_s_setprio(0);
        __builtin_amdgcn_s_barrier();        // all A(t)/B(t) reads complete

        // ---- ph2: stage A0(t+2) (WAR-safe now); MFMA m0-3 x k1 (regs) ----
        if (t + 2 < NT) stageA(t + 2, 0);
        __builtin_amdgcn_s_setprio(1);
        #pragma unroll
        for (int m = 0; m < 4; ++m)
            #pragma unroll
            for (int n = 0; n < 4; ++n)
                acc[m][n] = MFMA(afB[m], bfB[n], acc[m][n]);
        __builtin_amdgcn_s_setprio(0);
        __builtin_amdgcn_s_barrier();

        // ---- ph3: stage A1(t+2); MFMA m4-7 x k1 (regs) ----
        if (t + 2 < NT) stageA(t + 2, 1);
        __builtin_amdgcn_s_setprio(1);
        #pragma unroll
        for (int m = 0; m < 4; ++m)
            #pragma unroll
            for (int n = 0; n < 4; ++n)
                acc[4 + m][n] = MFMA(a2B[m], bfB[n], acc[4 + m][n]);
        __builtin_amdgcn_s_setprio(0);
        // loop-top vmcnt + barrier closes the tile
    }

    // epilogue: C/D layout col=lane&15, row=(lane>>4)*4+j (HW-verified)
    const int r0 = bm * BM + wr + ls * 4;
    const int c0 = bn * BN + wc + lr;
    #pragma unroll
    for (int n = 0; n < 4; ++n) {
        const int gc = c0 + n * 16;
        const float bv = bias[gc];
        #pragma unroll
        for (int m = 0; m < 8; ++m) {
            #pragma unroll
            for (int j = 0; j < 4; ++j) {
                const int gr = r0 + m * 16 + j;
                const float v = acc[m][n][j] + bv;
                if constexpr (OUT_BF16)
                    ((unsigned short*)Cvoid)[(size_t)gr * N + gc] = f2bf(v);
                else
                    ((float*)Cvoid)[(size_t)gr * N + gc] = v;
            }
        }
    }
}

// ---------------- per-token attention over heads (8x8 softmax) --------------
__global__ __launch_bounds__(256) void attn_heads(
        const unsigned short* __restrict__ qkv,   // [M][1536] bf16
        unsigned short* __restrict__ val,         // [M][512]  bf16
        int M) {
    const int t    = blockIdx.x * 4 + (threadIdx.x >> 6);
    const int lane = threadIdx.x & 63;
    const int h    = lane >> 3;
    const int c    = lane & 7;
    const unsigned short* base = qkv + (size_t)t * 1536;

    s16x8 q8 = *(const s16x8*)(base + h * 192 + c * 8);
    float qf[8];
    #pragma unroll
    for (int j = 0; j < 8; ++j) qf[j] = bf2f((unsigned short)q8[j]);

    float s[8];
    #pragma unroll
    for (int g = 0; g < 8; ++g) {
        s16x8 k8 = *(const s16x8*)(base + g * 192 + 64 + c * 8);
        float p = 0.f;
        #pragma unroll
        for (int j = 0; j < 8; ++j) p += qf[j] * bf2f((unsigned short)k8[j]);
        s[g] = p;
    }
    #pragma unroll
    for (int mask = 1; mask <= 4; mask <<= 1)
        #pragma unroll
        for (int g = 0; g < 8; ++g)
            s[g] += __shfl_xor(s[g], mask, 64);

    float mx = -1e30f;
    #pragma unroll
    for (int g = 0; g < 8; ++g) { s[g] *= 0.125f; mx = fmaxf(mx, s[g]); }
    float sum = 0.f;
    #pragma unroll
    for (int g = 0; g < 8; ++g) { s[g] = __expf(s[g] - mx); sum += s[g]; }
    const float inv = 1.f / sum;

    float acc[8] = {0.f,0.f,0.f,0.f,0.f,0.f,0.f,0.f};
    #pragma unroll
    for (int g = 0; g < 8; ++g) {
        s16x8 v8 = *(const s16x8*)(base + g * 192 + 128 + c * 8);
        const float ag = s[g] * inv;
        #pragma unroll
        for (int j = 0; j < 8; ++j) acc[j] += ag * bf2f((unsigned short)v8[j]);
    }
    s16x8 ov;
    #pragma unroll
    for (int j = 0; j < 8; ++j) ov[j] = (short)f2bf(acc[j]);
    *(s16x8*)(val + (size_t)t * 512 + h * 64 + c * 8) = ov;
}

// ---------------------------------------------------------------------------
extern "C" void kernel_launch(void* const* d_in, const int* in_sizes, int n_in,
                              void* d_out, int out_size, void* d_ws, size_t ws_size,
                              hipStream_t stream) {
    const float* x     = (const float*)d_in[0];
    const float* w_qkv = (const float*)d_in[1];
    const float* b_qkv = (const float*)d_in[2];
    const float* w_out = (const float*)d_in[3];
    const float* b_out = (const float*)d_in[4];
    float* out = (float*)d_out;

    const int DM = 512;
    const int M  = in_sizes[0] / DM;      // 61440 tokens

    unsigned short* xb    = (unsigned short*)d_ws;          // M*512
    unsigned short* wqkvb = xb + (size_t)M * DM;            // 1536*512
    unsigned short* woutb = wqkvb + (size_t)3 * DM * DM;    // 512*512
    unsigned short* qkvb  = woutb + (size_t)DM * DM;        // M*1536
    unsigned short* valb  = qkvb + (size_t)M * 3 * DM;      // M*512

    cvt_bf16<<<2048, 256, 0, stream>>>(x, xb, M * DM / 4);
    cvt_bf16<<<96,   256, 0, stream>>>(w_qkv, wqkvb, 3 * DM * DM / 4);
    cvt_bf16<<<32,   256, 0, stream>>>(w_out, woutb, DM * DM / 4);

    // GEMM1: qkv[M][1536] = x @ w_qkv^T + b_qkv (bf16 out). grid 240*6=1440
    gemm8p<512, true><<<dim3((M / 256) * (3 * DM / 256)), 512, 0, stream>>>(
        xb, wqkvb, b_qkv, qkvb, M, 3 * DM, 3 * DM / 256);

    // per-token attention over heads
    attn_heads<<<M / 4, 256, 0, stream>>>(qkvb, valb, M);

    // GEMM2: out[M][512] = val @ w_out^T + b_out (fp32 out). grid 240*2=480
    gemm8p<512, false><<<dim3((M / 256) * (DM / 256)), 512, 0, stream>>>(
        valb, woutb, b_out, out, M, DM, DM / 256);
}

// Round 18
// 299.953 us; speedup vs baseline: 1.5798x; 1.0290x over previous
//
#include <hip/hip_runtime.h>
#include <hip/hip_bf16.h>
#include <stdint.h>

typedef short    s16x8  __attribute__((ext_vector_type(8)));
typedef __bf16   bf16x8 __attribute__((ext_vector_type(8)));
typedef float    f32x4  __attribute__((ext_vector_type(4)));

__device__ __forceinline__ unsigned short f2bf(float f) {
    union { float f; unsigned u; } v; v.f = f;
    unsigned r = v.u + 0x7FFFu + ((v.u >> 16) & 1u);
    return (unsigned short)(r >> 16);
}
__device__ __forceinline__ float bf2f(unsigned short s) {
    union { unsigned u; float f; } v; v.u = ((unsigned)s) << 16;
    return v.f;
}

__device__ __forceinline__ void gload16(const void* g, void* l) {
    __builtin_amdgcn_global_load_lds(
        (const __attribute__((address_space(1))) void*)(uintptr_t)g,
        (__attribute__((address_space(3))) void*)(uintptr_t)l,
        16, 0, 0);
}

// ---------------- fp32 -> bf16 conversion (vectorized, grid-stride) ----------
__global__ __launch_bounds__(256) void cvt_bf16(const float* __restrict__ in,
                                                unsigned short* __restrict__ out,
                                                int n4) {
    int i = blockIdx.x * blockDim.x + threadIdx.x;
    int stride = gridDim.x * blockDim.x;
    for (; i < n4; i += stride) {
        const float4 v = *(const float4*)(in + (size_t)i * 4);
        ushort4 o;
        o.x = f2bf(v.x); o.y = f2bf(v.y); o.z = f2bf(v.z); o.w = f2bf(v.w);
        *(ushort4*)(out + (size_t)i * 4) = o;
    }
}

// ---------------- 128x128 bf16 GEMM, BK=64 — SESSION OPTIMUM (R11) ----------
// 4 waves (2x2), 64x64 C per wave, BK=64, NT=8 windows, LDS 64 KiB dbuf ->
// 2 blocks/CU. One vmcnt(0)+__syncthreads per window. T1 XCD swizzle,
// T2 source-XOR swizzle (gslot = slot ^ (row&7); 0 conflicts measured),
// T5 setprio. This plain 2-phase structure measured 130 us on GEMM1 —
// robust optimum across 8 attempted refinements (counted vmcnt, ring depth,
// fine/8-phase splits, bigger wave tiles, A-direct, fusions) at K=512.
template<int K, bool OUT_BF16>
__global__ __launch_bounds__(256, 2) void gemm128(
        const unsigned short* __restrict__ A,   // [M][K] bf16
        const unsigned short* __restrict__ B,   // [N][K] bf16
        const float* __restrict__ bias,         // [N] fp32
        void* __restrict__ Cvoid,               // [M][N] bf16 or fp32
        int M, int N, int ntn) {
    constexpr int BM = 128, BN = 128, BK = 64, NT = K / BK;   // NT = 8
    __shared__ __align__(16) unsigned short As[2][BM * BK];   // 2 x 16 KiB
    __shared__ __align__(16) unsigned short Bs[2][BN * BK];   // 2 x 16 KiB
    const int tid  = threadIdx.x;
    const int lane = tid & 63;
    const int wv   = tid >> 6;                  // 4 waves
    const int nwg  = (int)gridDim.x;
    const int wg   = ((int)blockIdx.x & 7) * (nwg >> 3) + ((int)blockIdx.x >> 3);
    const int bm   = wg / ntn;
    const int bn   = wg % ntn;
    const int wr   = (wv >> 1) * 64;    // wave M-offset in tile
    const int wc   = (wv & 1) * 64;     // wave N-offset in tile
    const int lr   = lane & 15;
    const int ls   = lane >> 4;         // k-slot 0..3 within a 32-col half

    const unsigned short* Ag = A + (size_t)bm * BM * K;
    const unsigned short* Bg = B + (size_t)bn * BN * K;

    auto stage = [&](int t) {
        char* la = (char*)As[t & 1];
        char* lb = (char*)Bs[t & 1];
        #pragma unroll
        for (int p = 0; p < 4; ++p) {
            const int c     = p * 256 + tid;
            const int row   = c >> 3;                  // 8 x 16B chunks per row
            const int slot  = c & 7;
            const int gslot = slot ^ (row & 7);        // T2 involution
            gload16(Ag + (size_t)row * K + t * BK + gslot * 8, la + c * 16);
            gload16(Bg + (size_t)row * K + t * BK + gslot * 8, lb + c * 16);
        }
    };
    auto frag = [&](const unsigned short* lds, int row, int ks) -> bf16x8 {
        const int slot = ks ^ (row & 7);
        return *(const bf16x8*)((const char*)lds + row * (BK * 2) + slot * 16);
    };

    f32x4 acc[4][4] = {};

    stage(0);

    #pragma unroll
    for (int t = 0; t < NT; ++t) {
        asm volatile("s_waitcnt vmcnt(0)" ::: "memory");  // own slab-t chunks done
        __syncthreads();               // all waves' chunks visible; prev slab
                                       // fully consumed (reads precede barrier)
        if (t + 1 < NT) stage(t + 1);  // overwrites slab read at iter t-1: safe

        bf16x8 af[2][4], bf[2][4];
        #pragma unroll
        for (int h = 0; h < 2; ++h) {
            #pragma unroll
            for (int m = 0; m < 4; ++m)
                af[h][m] = frag(As[t & 1], wr + m * 16 + lr, h * 4 + ls);
            #pragma unroll
            for (int n = 0; n < 4; ++n)
                bf[h][n] = frag(Bs[t & 1], wc + n * 16 + lr, h * 4 + ls);
        }

        __builtin_amdgcn_s_setprio(1);
        #pragma unroll
        for (int h = 0; h < 2; ++h)
            #pragma unroll
            for (int m = 0; m < 4; ++m)
                #pragma unroll
                for (int n = 0; n < 4; ++n)
                    acc[m][n] = __builtin_amdgcn_mfma_f32_16x16x32_bf16(
                        af[h][m], bf[h][n], acc[m][n], 0, 0, 0);
        __builtin_amdgcn_s_setprio(0);
    }

    // epilogue: C/D layout col=lane&15, row=(lane>>4)*4+j (HW-verified)
    const int r0 = bm * BM + wr + ls * 4;
    const int c0 = bn * BN + wc + lr;
    #pragma unroll
    for (int n = 0; n < 4; ++n) {
        const int gc = c0 + n * 16;
        const float bv = bias[gc];
        #pragma unroll
        for (int m = 0; m < 4; ++m) {
            #pragma unroll
            for (int j = 0; j < 4; ++j) {
                const int gr = r0 + m * 16 + j;
                const float v = acc[m][n][j] + bv;
                if constexpr (OUT_BF16)
                    ((unsigned short*)Cvoid)[(size_t)gr * N + gc] = f2bf(v);
                else
                    ((float*)Cvoid)[(size_t)gr * N + gc] = v;
            }
        }
    }
}

// ---------------- per-token attention over heads (8x8 softmax) --------------
__global__ __launch_bounds__(256) void attn_heads(
        const unsigned short* __restrict__ qkv,   // [M][1536] bf16
        unsigned short* __restrict__ val,         // [M][512]  bf16
        int M) {
    const int t    = blockIdx.x * 4 + (threadIdx.x >> 6);
    const int lane = threadIdx.x & 63;
    const int h    = lane >> 3;
    const int c    = lane & 7;
    const unsigned short* base = qkv + (size_t)t * 1536;

    s16x8 q8 = *(const s16x8*)(base + h * 192 + c * 8);
    float qf[8];
    #pragma unroll
    for (int j = 0; j < 8; ++j) qf[j] = bf2f((unsigned short)q8[j]);

    float s[8];
    #pragma unroll
    for (int g = 0; g < 8; ++g) {
        s16x8 k8 = *(const s16x8*)(base + g * 192 + 64 + c * 8);
        float p = 0.f;
        #pragma unroll
        for (int j = 0; j < 8; ++j) p += qf[j] * bf2f((unsigned short)k8[j]);
        s[g] = p;
    }
    #pragma unroll
    for (int mask = 1; mask <= 4; mask <<= 1)
        #pragma unroll
        for (int g = 0; g < 8; ++g)
            s[g] += __shfl_xor(s[g], mask, 64);

    float mx = -1e30f;
    #pragma unroll
    for (int g = 0; g < 8; ++g) { s[g] *= 0.125f; mx = fmaxf(mx, s[g]); }
    float sum = 0.f;
    #pragma unroll
    for (int g = 0; g < 8; ++g) { s[g] = __expf(s[g] - mx); sum += s[g]; }
    const float inv = 1.f / sum;

    float acc[8] = {0.f,0.f,0.f,0.f,0.f,0.f,0.f,0.f};
    #pragma unroll
    for (int g = 0; g < 8; ++g) {
        s16x8 v8 = *(const s16x8*)(base + g * 192 + 128 + c * 8);
        const float ag = s[g] * inv;
        #pragma unroll
        for (int j = 0; j < 8; ++j) acc[j] += ag * bf2f((unsigned short)v8[j]);
    }
    s16x8 ov;
    #pragma unroll
    for (int j = 0; j < 8; ++j) ov[j] = (short)f2bf(acc[j]);
    *(s16x8*)(val + (size_t)t * 512 + h * 64 + c * 8) = ov;
}

// ---------------------------------------------------------------------------
extern "C" void kernel_launch(void* const* d_in, const int* in_sizes, int n_in,
                              void* d_out, int out_size, void* d_ws, size_t ws_size,
                              hipStream_t stream) {
    const float* x     = (const float*)d_in[0];
    const float* w_qkv = (const float*)d_in[1];
    const float* b_qkv = (const float*)d_in[2];
    const float* w_out = (const float*)d_in[3];
    const float* b_out = (const float*)d_in[4];
    float* out = (float*)d_out;

    const int DM = 512;
    const int M  = in_sizes[0] / DM;      // 61440 tokens

    unsigned short* xb    = (unsigned short*)d_ws;          // M*512
    unsigned short* wqkvb = xb + (size_t)M * DM;            // 1536*512
    unsigned short* woutb = wqkvb + (size_t)3 * DM * DM;    // 512*512
    unsigned short* qkvb  = woutb + (size_t)DM * DM;        // M*1536
    unsigned short* valb  = qkvb + (size_t)M * 3 * DM;      // M*512

    cvt_bf16<<<2048, 256, 0, stream>>>(x, xb, M * DM / 4);
    cvt_bf16<<<96,   256, 0, stream>>>(w_qkv, wqkvb, 3 * DM * DM / 4);
    cvt_bf16<<<32,   256, 0, stream>>>(w_out, woutb, DM * DM / 4);

    // GEMM1: qkv[M][1536] = x @ w_qkv^T + b_qkv (bf16 out). grid 480*12=5760
    gemm128<512, true><<<dim3((M / 128) * (3 * DM / 128)), 256, 0, stream>>>(
        xb, wqkvb, b_qkv, qkvb, M, 3 * DM, 3 * DM / 128);

    // per-token attention over heads
    attn_heads<<<M / 4, 256, 0, stream>>>(qkvb, valb, M);

    // GEMM2: out[M][512] = val @ w_out^T + b_out (fp32 out). grid 480*4=1920
    gemm128<512, false><<<dim3((M / 128) * (DM / 128)), 256, 0, stream>>>(
        valb, woutb, b_out, out, M, DM, DM / 128);
}

// Round 19
// 257.366 us; speedup vs baseline: 1.8412x; 1.1655x over previous
//
#include <hip/hip_runtime.h>
#include <hip/hip_bf16.h>
#include <stdint.h>

typedef short    s16x8  __attribute__((ext_vector_type(8)));
typedef __bf16   bf16x8 __attribute__((ext_vector_type(8)));
typedef float    f32x4  __attribute__((ext_vector_type(4)));

__device__ __forceinline__ unsigned short f2bf(float f) {
    union { float f; unsigned u; } v; v.f = f;
    unsigned r = v.u + 0x7FFFu + ((v.u >> 16) & 1u);
    return (unsigned short)(r >> 16);
}
__device__ __forceinline__ float bf2f(unsigned short s) {
    union { unsigned u; float f; } v; v.u = ((unsigned)s) << 16;
    return v.f;
}

__device__ __forceinline__ void gload16(const void* g, void* l) {
    __builtin_amdgcn_global_load_lds(
        (const __attribute__((address_space(1))) void*)(uintptr_t)g,
        (__attribute__((address_space(3))) void*)(uintptr_t)l,
        16, 0, 0);
}

// ---------------- fp32 -> bf16 conversion (vectorized, grid-stride) ----------
__global__ __launch_bounds__(256) void cvt_bf16(const float* __restrict__ in,
                                                unsigned short* __restrict__ out,
                                                int n4) {
    int i = blockIdx.x * blockDim.x + threadIdx.x;
    int stride = gridDim.x * blockDim.x;
    for (; i < n4; i += stride) {
        const float4 v = *(const float4*)(in + (size_t)i * 4);
        ushort4 o;
        o.x = f2bf(v.x); o.y = f2bf(v.y); o.z = f2bf(v.z); o.w = f2bf(v.w);
        *(ushort4*)(out + (size_t)i * 4) = o;
    }
}

// ---------------- 128x128 bf16 GEMM, BK=64 — SESSION OPTIMUM (R11) ----------
// 4 waves (2x2), 64x64 C per wave, BK=64, NT=8 windows, LDS 64 KiB dbuf ->
// 2 blocks/CU. One vmcnt(0)+__syncthreads per window. T1 XCD swizzle,
// T2 source-XOR swizzle (gslot = slot ^ (row&7); 0 conflicts measured),
// T5 setprio. Robust optimum across 8 attempted refinements at K=512.
template<int K, bool OUT_BF16>
__global__ __launch_bounds__(256, 2) void gemm128(
        const unsigned short* __restrict__ A,   // [M][K] bf16
        const unsigned short* __restrict__ B,   // [N][K] bf16
        const float* __restrict__ bias,         // [N] fp32
        void* __restrict__ Cvoid,               // [M][N] bf16 or fp32
        int M, int N, int ntn) {
    constexpr int BM = 128, BN = 128, BK = 64, NT = K / BK;   // NT = 8
    __shared__ __align__(16) unsigned short As[2][BM * BK];   // 2 x 16 KiB
    __shared__ __align__(16) unsigned short Bs[2][BN * BK];   // 2 x 16 KiB
    const int tid  = threadIdx.x;
    const int lane = tid & 63;
    const int wv   = tid >> 6;                  // 4 waves
    const int nwg  = (int)gridDim.x;
    const int wg   = ((int)blockIdx.x & 7) * (nwg >> 3) + ((int)blockIdx.x >> 3);
    const int bm   = wg / ntn;
    const int bn   = wg % ntn;
    const int wr   = (wv >> 1) * 64;    // wave M-offset in tile
    const int wc   = (wv & 1) * 64;     // wave N-offset in tile
    const int lr   = lane & 15;
    const int ls   = lane >> 4;         // k-slot 0..3 within a 32-col half

    const unsigned short* Ag = A + (size_t)bm * BM * K;
    const unsigned short* Bg = B + (size_t)bn * BN * K;

    auto stage = [&](int t) {
        char* la = (char*)As[t & 1];
        char* lb = (char*)Bs[t & 1];
        #pragma unroll
        for (int p = 0; p < 4; ++p) {
            const int c     = p * 256 + tid;
            const int row   = c >> 3;                  // 8 x 16B chunks per row
            const int slot  = c & 7;
            const int gslot = slot ^ (row & 7);        // T2 involution
            gload16(Ag + (size_t)row * K + t * BK + gslot * 8, la + c * 16);
            gload16(Bg + (size_t)row * K + t * BK + gslot * 8, lb + c * 16);
        }
    };
    auto frag = [&](const unsigned short* lds, int row, int ks) -> bf16x8 {
        const int slot = ks ^ (row & 7);
        return *(const bf16x8*)((const char*)lds + row * (BK * 2) + slot * 16);
    };

    f32x4 acc[4][4] = {};

    stage(0);

    #pragma unroll
    for (int t = 0; t < NT; ++t) {
        asm volatile("s_waitcnt vmcnt(0)" ::: "memory");  // own slab-t chunks done
        __syncthreads();               // all waves' chunks visible; prev slab
                                       // fully consumed (reads precede barrier)
        if (t + 1 < NT) stage(t + 1);  // overwrites slab read at iter t-1: safe

        bf16x8 af[2][4], bf[2][4];
        #pragma unroll
        for (int h = 0; h < 2; ++h) {
            #pragma unroll
            for (int m = 0; m < 4; ++m)
                af[h][m] = frag(As[t & 1], wr + m * 16 + lr, h * 4 + ls);
            #pragma unroll
            for (int n = 0; n < 4; ++n)
                bf[h][n] = frag(Bs[t & 1], wc + n * 16 + lr, h * 4 + ls);
        }

        __builtin_amdgcn_s_setprio(1);
        #pragma unroll
        for (int h = 0; h < 2; ++h)
            #pragma unroll
            for (int m = 0; m < 4; ++m)
                #pragma unroll
                for (int n = 0; n < 4; ++n)
                    acc[m][n] = __builtin_amdgcn_mfma_f32_16x16x32_bf16(
                        af[h][m], bf[h][n], acc[m][n], 0, 0, 0);
        __builtin_amdgcn_s_setprio(0);
    }

    // epilogue: C/D layout col=lane&15, row=(lane>>4)*4+j (HW-verified)
    const int r0 = bm * BM + wr + ls * 4;
    const int c0 = bn * BN + wc + lr;
    #pragma unroll
    for (int n = 0; n < 4; ++n) {
        const int gc = c0 + n * 16;
        const float bv = bias[gc];
        #pragma unroll
        for (int m = 0; m < 4; ++m) {
            #pragma unroll
            for (int j = 0; j < 4; ++j) {
                const int gr = r0 + m * 16 + j;
                const float v = acc[m][n][j] + bv;
                if constexpr (OUT_BF16)
                    ((unsigned short*)Cvoid)[(size_t)gr * N + gc] = f2bf(v);
                else
                    ((float*)Cvoid)[(size_t)gr * N + gc] = v;
            }
        }
    }
}

// ---------------- per-token attention over heads (8x8 softmax) --------------
__global__ __launch_bounds__(256) void attn_heads(
        const unsigned short* __restrict__ qkv,   // [M][1536] bf16
        unsigned short* __restrict__ val,         // [M][512]  bf16
        int M) {
    const int t    = blockIdx.x * 4 + (threadIdx.x >> 6);
    const int lane = threadIdx.x & 63;
    const int h    = lane >> 3;
    const int c    = lane & 7;
    const unsigned short* base = qkv + (size_t)t * 1536;

    s16x8 q8 = *(const s16x8*)(base + h * 192 + c * 8);
    float qf[8];
    #pragma unroll
    for (int j = 0; j < 8; ++j) qf[j] = bf2f((unsigned short)q8[j]);

    float s[8];
    #pragma unroll
    for (int g = 0; g < 8; ++g) {
        s16x8 k8 = *(const s16x8*)(base + g * 192 + 64 + c * 8);
        float p = 0.f;
        #pragma unroll
        for (int j = 0; j < 8; ++j) p += qf[j] * bf2f((unsigned short)k8[j]);
        s[g] = p;
    }
    #pragma unroll
    for (int mask = 1; mask <= 4; mask <<= 1)
        #pragma unroll
        for (int g = 0; g < 8; ++g)
            s[g] += __shfl_xor(s[g], mask, 64);

    float mx = -1e30f;
    #pragma unroll
    for (int g = 0; g < 8; ++g) { s[g] *= 0.125f; mx = fmaxf(mx, s[g]); }
    float sum = 0.f;
    #pragma unroll
    for (int g = 0; g < 8; ++g) { s[g] = __expf(s[g] - mx); sum += s[g]; }
    const float inv = 1.f / sum;

    float acc[8] = {0.f,0.f,0.f,0.f,0.f,0.f,0.f,0.f};
    #pragma unroll
    for (int g = 0; g < 8; ++g) {
        s16x8 v8 = *(const s16x8*)(base + g * 192 + 128 + c * 8);
        const float ag = s[g] * inv;
        #pragma unroll
        for (int j = 0; j < 8; ++j) acc[j] += ag * bf2f((unsigned short)v8[j]);
    }
    s16x8 ov;
    #pragma unroll
    for (int j = 0; j < 8; ++j) ov[j] = (short)f2bf(acc[j]);
    *(s16x8*)(val + (size_t)t * 512 + h * 64 + c * 8) = ov;
}

// ---------------------------------------------------------------------------
extern "C" void kernel_launch(void* const* d_in, const int* in_sizes, int n_in,
                              void* d_out, int out_size, void* d_ws, size_t ws_size,
                              hipStream_t stream) {
    const float* x     = (const float*)d_in[0];
    const float* w_qkv = (const float*)d_in[1];
    const float* b_qkv = (const float*)d_in[2];
    const float* w_out = (const float*)d_in[3];
    const float* b_out = (const float*)d_in[4];
    float* out = (float*)d_out;

    const int DM = 512;
    const int M  = in_sizes[0] / DM;      // 61440 tokens

    unsigned short* xb    = (unsigned short*)d_ws;          // M*512
    unsigned short* wqkvb = xb + (size_t)M * DM;            // 1536*512
    unsigned short* woutb = wqkvb + (size_t)3 * DM * DM;    // 512*512
    unsigned short* qkvb  = woutb + (size_t)DM * DM;        // M*1536
    // CRITICAL (R18 post-mortem): val ALIASES xb. Working set of the
    // attn->GEMM2 chain = xb(63MB) + qkvb(189MB) = 252MB <= 256MB L3, so the
    // val round-trip stays Infinity-Cache-resident (~40 us faster than a
    // fresh buffer, which pushes the footprint past L3). Safe: stream order
    // is cvt_x -> GEMM1 -> attn -> GEMM2, and cvt_x rewrites xb every call.
    unsigned short* valb  = xb;

    cvt_bf16<<<2048, 256, 0, stream>>>(x, xb, M * DM / 4);
    cvt_bf16<<<96,   256, 0, stream>>>(w_qkv, wqkvb, 3 * DM * DM / 4);
    cvt_bf16<<<32,   256, 0, stream>>>(w_out, woutb, DM * DM / 4);

    // GEMM1: qkv[M][1536] = x @ w_qkv^T + b_qkv (bf16 out). grid 480*12=5760
    gemm128<512, true><<<dim3((M / 128) * (3 * DM / 128)), 256, 0, stream>>>(
        xb, wqkvb, b_qkv, qkvb, M, 3 * DM, 3 * DM / 128);

    // per-token attention over heads
    attn_heads<<<M / 4, 256, 0, stream>>>(qkvb, valb, M);

    // GEMM2: out[M][512] = val @ w_out^T + b_out (fp32 out). grid 480*4=1920
    gemm128<512, false><<<dim3((M / 128) * (DM / 128)), 256, 0, stream>>>(
        valb, woutb, b_out, out, M, DM, DM / 128);
}